// Round 10
// baseline (264.085 us; speedup 1.0000x reference)
//
#include <hip/hip_runtime.h>

// Shapes fixed by the reference: B=8, C=128, H=W=64 -> S=4096. All I/O fp32.
#define BB 8
#define CC 128
#define SS 4096
#define KT 64             // kv tile per iteration
#define NSPLIT 2          // KV split factor (flash-style partial softmax)
#define HKV (SS / NSPLIT) // kv tokens per block = 2048
#define NIT (HKV / KT)    // 32 kv tiles per block
#define SCALE 0.015625f   // 1/sqrt(H*W) = 1/64

typedef __attribute__((ext_vector_type(8))) short sh8;   // 8 bf16 (MFMA A/B frag)
typedef __attribute__((ext_vector_type(4))) float f32x4; // MFMA C/D frag

__device__ __forceinline__ float b2f(unsigned short u) {
    union { unsigned int i; float f; } x; x.i = ((unsigned int)u) << 16; return x.f;
}
__device__ __forceinline__ unsigned short f2b(float f) {  // RNE
    union { float f; unsigned int i; } x; x.f = f;
    unsigned int r = x.i + 0x7fff + ((x.i >> 16) & 1);
    return (unsigned short)(r >> 16);
}
__device__ __forceinline__ unsigned short rhu(float f) {  // round-half-up, 2 VALU
    union { float f; unsigned int i; } x; x.f = f;
    return (unsigned short)((x.i + 0x8000) >> 16);
}
// pack 2 f32 -> 2 bf16 in one dword (lo = first arg). No builtin on gfx950.
__device__ __forceinline__ unsigned int cvtpk(float lo, float hi) {
    unsigned int r;
    asm("v_cvt_pk_bf16_f32 %0, %1, %2" : "=v"(r) : "v"(lo), "v"(hi));
    return r;
}

// async 16B global->LDS DMA (lane i writes lds_base + i*16; LDS base wave-uniform)
__device__ __forceinline__ void dma16(const void* g, void* l) {
    __builtin_amdgcn_global_load_lds((const __attribute__((address_space(1))) void*)g,
                                     (__attribute__((address_space(3))) void*)l,
                                     16, 0, 0);
}

// ---------------------------------------------------------------------------
// cvt: V fp32->bf16 (layout preserved) + W/bias fp32->bf16 + flag zeroing.
// blocks 0..511: V. blocks 512..519: Wq|Wk|bq|bk concat (33024 elems).
// block 512 additionally zeroes the 256 merge flags (stream-ordered < attn).
// ---------------------------------------------------------------------------
__global__ __launch_bounds__(256) void cvt_kernel(
    const float* __restrict__ vimg,
    const float* __restrict__ Wq, const float* __restrict__ Wk,
    const float* __restrict__ bq, const float* __restrict__ bk,
    unsigned short* __restrict__ Vbuf,
    unsigned short* __restrict__ Wqb, unsigned short* __restrict__ Wkb,
    unsigned short* __restrict__ bqb, unsigned short* __restrict__ bkb,
    int* __restrict__ flags)
{
    const int bx = blockIdx.x, tid = threadIdx.x;
    if (bx < 512) {
        const size_t base = (size_t)bx * 8192 + tid * 4;
        #pragma unroll
        for (int it = 0; it < 8; ++it) {
            const size_t i = base + (size_t)it * 1024;
            float4 v = *(const float4*)(vimg + i);
            ushort4 o;
            o.x = f2b(v.x); o.y = f2b(v.y); o.z = f2b(v.z); o.w = f2b(v.w);
            *(ushort4*)(Vbuf + i) = o;
        }
    } else {
        if (bx == 512) flags[tid] = 0;   // 256 merge flags
        const int w = bx - 512;  // 0..7
        for (int e = w * 256 + tid; e < 33024; e += 2048) {
            float v; unsigned short* dst;
            if (e < 16384)      { v = Wq[e];         dst = Wqb + e; }
            else if (e < 32768) { v = Wk[e - 16384]; dst = Wkb + (e - 16384); }
            else if (e < 32896) { v = bq[e - 32768]; dst = bqb + (e - 32768); }
            else                { v = bk[e - 32896]; dst = bkb + (e - 32896); }
            *dst = f2b(v);
        }
    }
}

// ---------------------------------------------------------------------------
// Projection (bf16 weights), LDS-transposed staging, coalesced LDS epilogue.
// outTok[b][s][o] = sum_c img[b][c][s] * W[o][c] + bias[o]
// grid=(64, 8, 2): z=0 -> Q, z=1 -> K.  (round-6 verbatim, measured)
// ---------------------------------------------------------------------------
__global__ __launch_bounds__(256) void proj_kernel(
    const float* __restrict__ qimg, const float* __restrict__ kimg,
    const unsigned short* __restrict__ Wqb, const unsigned short* __restrict__ Wkb,
    const unsigned short* __restrict__ bqb, const unsigned short* __restrict__ bkb,
    unsigned short* __restrict__ Qbuf, unsigned short* __restrict__ Kbuf)
{
    __shared__ float ilds[128 * 69];   // 128 chans x (64 tokens + 5 pad) = 35,328 B

    const int z = blockIdx.z;
    const float* img = (z == 0) ? qimg : kimg;
    const unsigned short* Wb = (z == 0) ? Wqb : Wkb;
    const unsigned short* bias = (z == 0) ? bqb : bkb;
    unsigned short* outTok = (z == 0) ? Qbuf : Kbuf;

    const int tid  = threadIdx.x;
    const int wave = tid >> 6;
    const int lane = tid & 63;
    const int l15  = lane & 15;
    const int quad = lane >> 4;
    const int b     = blockIdx.y;
    const int stile = blockIdx.x;

    const float* gbase = img + (size_t)b * CC * SS + stile * 64;
    #pragma unroll
    for (int i = 0; i < 8; ++i) {
        const int l = tid + 256 * i;          // 0..2047
        const int row = l >> 4, col = (l & 15) * 4;
        float4 v = *(const float4*)(gbase + (size_t)row * SS + col);
        float* d = ilds + row * 69 + col;
        d[0] = v.x; d[1] = v.y; d[2] = v.z; d[3] = v.w;
    }
    __syncthreads();

    const int tcol = wave * 16 + l15;
    sh8 a[4];
    #pragma unroll
    for (int kk = 0; kk < 4; ++kk)
        #pragma unroll
        for (int j = 0; j < 8; ++j)
            a[kk][j] = (short)rhu(ilds[(32 * kk + quad * 8 + j) * 69 + tcol]);

    f32x4 acc[8];
    #pragma unroll
    for (int nt = 0; nt < 8; ++nt) acc[nt] = (f32x4){0.f, 0.f, 0.f, 0.f};

    #pragma unroll
    for (int nt = 0; nt < 8; ++nt) {
        const unsigned short* wp = Wb + (size_t)(16 * nt + l15) * CC + quad * 8;
        #pragma unroll
        for (int kk = 0; kk < 4; ++kk) {
            sh8 bf = *(const sh8*)(wp + 32 * kk);
            acc[nt] = __builtin_amdgcn_mfma_f32_16x16x32_bf16(a[kk], bf, acc[nt], 0, 0, 0);
        }
    }

    __syncthreads();   // all ilds A-frag reads done; safe to alias
    unsigned short* oT = (unsigned short*)ilds;   // [64 s][132 o] ushorts
    #pragma unroll
    for (int nt = 0; nt < 8; ++nt) {
        const int o = 16 * nt + l15;
        const float bv = b2f(bias[o]);
        #pragma unroll
        for (int r = 0; r < 4; ++r) {
            const int sl = wave * 16 + quad * 4 + r;
            oT[sl * 132 + o] = f2b(acc[nt][r] + bv);   // 2-way banks (free)
        }
    }
    __syncthreads();

    unsigned short* orow = outTok + ((size_t)b * SS + stile * 64) * CC;
    #pragma unroll
    for (int i = 0; i < 8; ++i) {
        const int idx = tid + 256 * i;      // 0..2047
        const int s = idx >> 5, o4 = (idx & 31) * 4;
        *(ushort4*)(orow + (size_t)s * CC + o4) = *(const ushort4*)(oT + s * 132 + o4);
    }
}

// ---------------------------------------------------------------------------
// Flash attention v7 = round-9 loop VERBATIM (best measured, 78.5 us) +
// FUSED last-block combine:
//   each (b,qt) pair of split-KV blocks stores packed partials (unchanged:
//   row span [qt*128,+128) f32 = [256 B half0 bf16 | 256 B half1]) + Lsum,
//   then __threadfence + atomicAdd on flag[b][qt]; the SECOND finisher does
//   acquire fence, re-reads both partials (own = L2-hot) + LDS-staged Q
//   residual, writes the final f32 tile. Order-independent => deterministic.
//   Cross-XCD visibility = device-scope fence/atomic protocol (G16).
// Block: 4 waves x 32 q = 128 q over HKV=2048; grid 512 = 2 blocks/CU.
// LDS 65,536 B: K dbuf 2x16 KB [0,32K), V dbuf 2x16 KB [32K,64K);
// epilogue oT ushort[128][136], then merge rS ushort[128][133], alias front.
// ---------------------------------------------------------------------------
__global__ __launch_bounds__(256, 2) void attn_kernel(
    const unsigned short* __restrict__ Qbuf,  // (B,S,C) bf16 token-major
    const unsigned short* __restrict__ Kbuf,  // (B,S,C) bf16 token-major
    const unsigned short* __restrict__ Vbuf,  // (B,C,S) bf16 channel-major
    float* __restrict__ Oout,                 // (B,C,S) fp32 rows w/ packed partials
    float* __restrict__ Lsum,                 // (NSPLIT,B,S) f32 partial sums
    int* __restrict__ flags)                  // (B,32) merge flags, pre-zeroed
{
    __shared__ __align__(16) unsigned char smem[65536];

    const int tid  = threadIdx.x;
    const int wave = tid >> 6;
    const int lane = tid & 63;
    const int l15  = lane & 15;
    const int quad = lane >> 4;
    const int wgid = blockIdx.x;
    const int b    = wgid & 7;          // batch == XCD (L2 holds one batch's K/V)
    const int half = (wgid >> 3) & 1;   // KV half
    const int qt   = wgid >> 4;         // 0..31, 128 queries each
    const int qbase = qt * 128 + wave * 32;
    const int tok0  = half * HKV;

    const unsigned short* kbp = Kbuf + (size_t)b * SS * CC;
    const unsigned short* vbp = Vbuf + (size_t)b * CC * SS;

    // Q frags (B operand of swapped QK)
    sh8 aq[2][4];
    #pragma unroll
    for (int m = 0; m < 2; ++m) {
        const unsigned short* qp = Qbuf + ((size_t)b * SS + qbase + m * 16 + l15) * CC + quad * 8;
        #pragma unroll
        for (int kk = 0; kk < 4; ++kk) aq[m][kk] = *(const sh8*)(qp + 32 * kk);
    }

    // DMA source offsets (bytes), constant across iterations
    int kGO[4], vGO[4];
    #pragma unroll
    for (int j = 0; j < 4; ++j) {
        const int krow = wave * 16 + j * 4 + quad;
        const int sx = (krow & 3) | ((krow >> 1) & 4);
        kGO[j] = krow * 256 + (((lane & 15) ^ sx) << 4);
        const int vrow = (wave * 4 + j) * 8 + (lane >> 3);
        vGO[j] = vrow * 8192 + (((lane & 7) ^ ((lane >> 3) & 7)) << 4);
    }

    // K read addressing: permuted row per frag n; swizzle term == l15&7 for all n
    int krb[4];
    #pragma unroll
    for (int n = 0; n < 4; ++n)
        krb[n] = (32 * (n >> 1) + 8 * (l15 >> 2) + 4 * (n & 1) + (l15 & 3)) * 256;
    const int krs = l15 & 7;

    f32x4 oacc[2][8];
    #pragma unroll
    for (int m = 0; m < 2; ++m)
        #pragma unroll
        for (int ct = 0; ct < 8; ++ct) oacc[m][ct] = (f32x4){0.f, 0.f, 0.f, 0.f};
    float lsum[2] = {0.f, 0.f};

    const char* gk0 = (const char*)kbp + (size_t)tok0 * 256;
    const char* gv0 = (const char*)vbp + (size_t)tok0 * 2;

    // prologue: stage K[0], V[0] into buffer 0
    #pragma unroll
    for (int j = 0; j < 4; ++j) {
        dma16(gk0 + kGO[j], smem + (wave * 4 + j) * 1024);
        dma16(gv0 + vGO[j], smem + 32768 + (wave * 4 + j) * 1024);
    }

    for (int it = 0; it < NIT; ++it) {
        unsigned char* kb = smem + ((it & 1) << 14);
        unsigned char* vb = smem + 32768 + ((it & 1) << 14);

        // one barrier/iter: drains own DMA (vmcnt) + own LDS reads (lgkm),
        // then syncs -> K[it],V[it] resident and other buffers reusable.
        __syncthreads();

        // issue next-tile DMA into the other buffers; lands by next barrier
        if (it + 1 < NIT) {
            const char* gk = gk0 + (size_t)(it + 1) * KT * 256;
            const char* gv = gv0 + (size_t)(it + 1) * KT * 2;
            unsigned char* kbn = smem + (((it + 1) & 1) << 14);
            unsigned char* vbn = smem + 32768 + (((it + 1) & 1) << 14);
            #pragma unroll
            for (int j = 0; j < 4; ++j) {
                dma16(gk + kGO[j], kbn + (wave * 4 + j) * 1024);
                dma16(gv + vGO[j], vbn + (wave * 4 + j) * 1024);
            }
        }

        // --- S^T = K Q^T with permuted K rows ---
        f32x4 sacc[2][4];
        #pragma unroll
        for (int m = 0; m < 2; ++m)
            #pragma unroll
            for (int n = 0; n < 4; ++n) sacc[m][n] = (f32x4){0.f, 0.f, 0.f, 0.f};
        __builtin_amdgcn_s_setprio(1);
        #pragma unroll
        for (int n = 0; n < 4; ++n) {
            #pragma unroll
            for (int kk = 0; kk < 4; ++kk) {
                sh8 kf = *(const sh8*)(kb + krb[n] + (((4 * kk + quad) ^ krs) << 4));
                sacc[0][n] = __builtin_amdgcn_mfma_f32_16x16x32_bf16(kf, aq[0][kk], sacc[0][n], 0, 0, 0);
                sacc[1][n] = __builtin_amdgcn_mfma_f32_16x16x32_bf16(kf, aq[1][kk], sacc[1][n], 0, 0, 0);
            }
        }
        __builtin_amdgcn_s_setprio(0);

        // --- softmax fully in-register: exp, accumulate, pack to PV A-frags ---
        union { sh8 v; unsigned int d[4]; } pa[2][2];
        #pragma unroll
        for (int m = 0; m < 2; ++m) {
            float p[4][4];
            #pragma unroll
            for (int n = 0; n < 4; ++n)
                #pragma unroll
                for (int r = 0; r < 4; ++r) {
                    p[n][r] = __expf(sacc[m][n][r] * SCALE);
                    lsum[m] += p[n][r];
                }
            #pragma unroll
            for (int kp = 0; kp < 2; ++kp) {
                pa[m][kp].d[0] = cvtpk(p[2 * kp][0],     p[2 * kp][1]);
                pa[m][kp].d[1] = cvtpk(p[2 * kp][2],     p[2 * kp][3]);
                pa[m][kp].d[2] = cvtpk(p[2 * kp + 1][0], p[2 * kp + 1][1]);
                pa[m][kp].d[3] = cvtpk(p[2 * kp + 1][2], p[2 * kp + 1][3]);
            }
        }

        // --- PV: P from registers, V from LDS (8 frag reads per kp) ---
        __builtin_amdgcn_s_setprio(1);
        #pragma unroll
        for (int kp = 0; kp < 2; ++kp) {
            #pragma unroll
            for (int ct = 0; ct < 8; ++ct) {
                sh8 bv = *(const sh8*)(vb + (16 * ct + l15) * 128
                                          + (((kp * 4 + quad) ^ (l15 & 7)) << 4));
                oacc[0][ct] = __builtin_amdgcn_mfma_f32_16x16x32_bf16(pa[0][kp].v, bv, oacc[0][ct], 0, 0, 0);
                oacc[1][ct] = __builtin_amdgcn_mfma_f32_16x16x32_bf16(pa[1][kp].v, bv, oacc[1][ct], 0, 0, 0);
            }
        }
        __builtin_amdgcn_s_setprio(0);
    }

    // --- total row-sum: add across the 4 quads holding the same query ---
    #pragma unroll
    for (int m = 0; m < 2; ++m) {
        lsum[m] += __shfl_xor(lsum[m], 16, 64);
        lsum[m] += __shfl_xor(lsum[m], 32, 64);
    }
    if (quad == 0) {
        float* lp = Lsum + ((size_t)half * BB + b) * SS + qbase;
        lp[l15]      = lsum[0];
        lp[16 + l15] = lsum[1];
    }

    __syncthreads();   // all K/V-buffer reads done before aliasing smem

    // --- epilogue: unnormalized O -> bf16, LDS transpose, contiguous store ---
    unsigned short* oT = (unsigned short*)smem;   // [128 c][136 pad] ushorts
    #pragma unroll
    for (int m = 0; m < 2; ++m)
        #pragma unroll
        for (int ct = 0; ct < 8; ++ct) {
            const int c  = 16 * ct + l15;
            const int q0 = wave * 32 + m * 16 + quad * 4;
            ushort4 o;
            o.x = rhu(oacc[m][ct][0]); o.y = rhu(oacc[m][ct][1]);
            o.z = rhu(oacc[m][ct][2]); o.w = rhu(oacc[m][ct][3]);
            *(ushort4*)(oT + c * 136 + q0) = o;
        }
    __syncthreads();

    char* ob = (char*)Oout;
    #pragma unroll
    for (int i = 0; i < 16; ++i) {
        const int idx = tid + 256 * i;        // 0..4095
        const int c = idx >> 5, q4 = (idx & 31) * 4;
        const size_t rb = ((size_t)(b * CC + c) * SS + (size_t)qt * 128) * 4;
        *(ushort4*)(ob + rb + half * 256 + q4 * 2) = *(const ushort4*)(oT + c * 136 + q4);
    }

    // --- fused combine: second finisher of the (b,qt) pair merges ---
    __threadfence();                 // release: partials + Lsum device-visible
    __syncthreads();                 // all threads' stores fenced; oT reads done
    if (tid == 0)
        *(volatile int*)smem = atomicAdd(&flags[b * 32 + qt], 1);
    __syncthreads();
    const int old = *(volatile int*)smem;
    if (old == 0) return;            // first finisher: done (uniform exit)

    __threadfence();                 // acquire: see peer's partials

    // stage residual Q slab (128 tok x 128 c) into LDS, coalesced
    unsigned short (*rS)[133] = (unsigned short(*)[133])smem;  // 34,048 B
    const unsigned short* qb2 = Qbuf + ((size_t)b * SS + qt * 128) * CC;
    #pragma unroll
    for (int i = 0; i < 16; ++i) {
        const int idx = tid + 256 * i;   // 0..4095
        const int s = idx >> 5, c4 = (idx & 31) * 4;
        *(ushort4*)(&rS[s][c4]) = *(const ushort4*)(qb2 + (size_t)s * CC + c4);
    }

    const int s0l = (tid & 31) * 4;      // this thread's 4 tokens (local)
    float4 l0 = *(const float4*)(Lsum + (size_t)b * SS + qt * 128 + s0l);
    float4 l1 = *(const float4*)(Lsum + ((size_t)BB + b) * SS + qt * 128 + s0l);
    float rinv[4];
    rinv[0] = 1.f / (l0.x + l1.x); rinv[1] = 1.f / (l0.y + l1.y);
    rinv[2] = 1.f / (l0.z + l1.z); rinv[3] = 1.f / (l0.w + l1.w);
    __syncthreads();                 // rS staged

    const int coff = tid >> 5;           // 8 c-rows per pass, 16 passes
    for (int k = 0; k < 16; ++k) {
        const int c = coff + 8 * k;
        const size_t rb = (size_t)(b * CC + c) * SS + (size_t)qt * 128;  // f32 idx
        ushort4 p0 = *(const ushort4*)((const char*)Oout + rb * 4 + s0l * 2);
        ushort4 p1 = *(const ushort4*)((const char*)Oout + rb * 4 + 256 + s0l * 2);
        float4 o;
        o.x = (b2f(p0.x) + b2f(p1.x)) * rinv[0] + b2f(rS[s0l + 0][c]);
        o.y = (b2f(p0.y) + b2f(p1.y)) * rinv[1] + b2f(rS[s0l + 1][c]);
        o.z = (b2f(p0.z) + b2f(p1.z)) * rinv[2] + b2f(rS[s0l + 2][c]);
        o.w = (b2f(p0.w) + b2f(p1.w)) * rinv[3] + b2f(rS[s0l + 3][c]);
        *(float4*)(Oout + rb + s0l) = o;   // exclusive owner: no race
    }
}

extern "C" void kernel_launch(void* const* d_in, const int* in_sizes, int n_in,
                              void* d_out, int out_size, void* d_ws, size_t ws_size,
                              hipStream_t stream) {
    const float* qimg = (const float*)d_in[0];
    const float* kimg = (const float*)d_in[1];
    const float* vimg = (const float*)d_in[2];
    const float* Wq   = (const float*)d_in[3];
    const float* bq   = (const float*)d_in[4];
    const float* Wk   = (const float*)d_in[5];
    const float* bk   = (const float*)d_in[6];
    float* out = (float*)d_out;

    // workspace map (~24.6 MB): partials live inside d_out (half regions)
    unsigned short* Qbuf = (unsigned short*)d_ws;                    // 8 MB
    unsigned short* Kbuf = Qbuf + (size_t)BB * SS * CC;              // 8 MB
    unsigned short* Vbuf = Kbuf + (size_t)BB * SS * CC;              // 8 MB
    unsigned short* Wqb  = Vbuf + (size_t)BB * SS * CC;              // 32 KB
    unsigned short* Wkb  = Wqb + CC * CC;                            // 32 KB
    unsigned short* bqb  = Wkb + CC * CC;
    unsigned short* bkb  = bqb + CC;
    float* Lsum = (float*)(bkb + CC);                                // 256 KB
    int* flags  = (int*)(Lsum + (size_t)NSPLIT * BB * SS);           // 1 KB

    cvt_kernel<<<dim3(520), 256, 0, stream>>>(vimg, Wq, Wk, bq, bk,
                                              Vbuf, Wqb, Wkb, bqb, bkb, flags);
    proj_kernel<<<dim3(SS / 64, BB, 2), 256, 0, stream>>>(
        qimg, kimg, Wqb, Wkb, bqb, bkb, Qbuf, Kbuf);
    attn_kernel<<<dim3(NSPLIT * BB * (SS / 128)), 256, 0, stream>>>(
        Qbuf, Kbuf, Vbuf, out, Lsum, flags);
}

// Round 12
// 195.789 us; speedup vs baseline: 1.3488x; 1.3488x over previous
//
#include <hip/hip_runtime.h>

// Shapes fixed by the reference: B=8, C=128, H=W=64 -> S=4096. All I/O fp32.
#define BB 8
#define CC 128
#define SS 4096
#define KT 64             // kv tile per iteration
#define NSPLIT 2          // KV split factor (flash-style partial softmax)
#define HKV (SS / NSPLIT) // kv tokens per block = 2048
#define NIT (HKV / KT)    // 32 kv tiles per block
#define SCALE 0.015625f   // 1/sqrt(H*W) = 1/64

typedef __attribute__((ext_vector_type(8))) short sh8;   // 8 bf16 (MFMA A/B frag)
typedef __attribute__((ext_vector_type(4))) float f32x4; // MFMA C/D frag

__device__ __forceinline__ float b2f(unsigned short u) {
    union { unsigned int i; float f; } x; x.i = ((unsigned int)u) << 16; return x.f;
}
__device__ __forceinline__ unsigned short f2b(float f) {  // RNE
    union { float f; unsigned int i; } x; x.f = f;
    unsigned int r = x.i + 0x7fff + ((x.i >> 16) & 1);
    return (unsigned short)(r >> 16);
}
__device__ __forceinline__ unsigned short rhu(float f) {  // round-half-up, 2 VALU
    union { float f; unsigned int i; } x; x.f = f;
    return (unsigned short)((x.i + 0x8000) >> 16);
}
// pack 2 f32 -> 2 bf16 in one dword (lo = first arg). No builtin on gfx950.
__device__ __forceinline__ unsigned int cvtpk(float lo, float hi) {
    unsigned int r;
    asm("v_cvt_pk_bf16_f32 %0, %1, %2" : "=v"(r) : "v"(lo), "v"(hi));
    return r;
}

// async 16B global->LDS DMA (lane i writes lds_base + i*16; LDS base wave-uniform)
__device__ __forceinline__ void dma16(const void* g, void* l) {
    __builtin_amdgcn_global_load_lds((const __attribute__((address_space(1))) void*)g,
                                     (__attribute__((address_space(3))) void*)l,
                                     16, 0, 0);
}

// ---------------------------------------------------------------------------
// cvt: V fp32->bf16 (layout preserved) + W/bias fp32->bf16 (one-time).
// blocks 0..511: V. blocks 512..519: Wq|Wk|bq|bk concat (33024 elems).
// (round-9 verbatim)
// ---------------------------------------------------------------------------
__global__ __launch_bounds__(256) void cvt_kernel(
    const float* __restrict__ vimg,
    const float* __restrict__ Wq, const float* __restrict__ Wk,
    const float* __restrict__ bq, const float* __restrict__ bk,
    unsigned short* __restrict__ Vbuf,
    unsigned short* __restrict__ Wqb, unsigned short* __restrict__ Wkb,
    unsigned short* __restrict__ bqb, unsigned short* __restrict__ bkb)
{
    const int bx = blockIdx.x, tid = threadIdx.x;
    if (bx < 512) {
        const size_t base = (size_t)bx * 8192 + tid * 4;
        #pragma unroll
        for (int it = 0; it < 8; ++it) {
            const size_t i = base + (size_t)it * 1024;
            float4 v = *(const float4*)(vimg + i);
            ushort4 o;
            o.x = f2b(v.x); o.y = f2b(v.y); o.z = f2b(v.z); o.w = f2b(v.w);
            *(ushort4*)(Vbuf + i) = o;
        }
    } else {
        const int w = bx - 512;  // 0..7
        for (int e = w * 256 + tid; e < 33024; e += 2048) {
            float v; unsigned short* dst;
            if (e < 16384)      { v = Wq[e];         dst = Wqb + e; }
            else if (e < 32768) { v = Wk[e - 16384]; dst = Wkb + (e - 16384); }
            else if (e < 32896) { v = bq[e - 32768]; dst = bqb + (e - 32768); }
            else                { v = bk[e - 32896]; dst = bkb + (e - 32896); }
            *dst = f2b(v);
        }
    }
}

// ---------------------------------------------------------------------------
// Projection (bf16 weights), LDS-transposed staging, coalesced LDS epilogue.
// outTok[b][s][o] = sum_c img[b][c][s] * W[o][c] + bias[o]
// grid=(64, 8, 2): z=0 -> Q, z=1 -> K.  (round-6/9 verbatim, measured)
// ---------------------------------------------------------------------------
__global__ __launch_bounds__(256) void proj_kernel(
    const float* __restrict__ qimg, const float* __restrict__ kimg,
    const unsigned short* __restrict__ Wqb, const unsigned short* __restrict__ Wkb,
    const unsigned short* __restrict__ bqb, const unsigned short* __restrict__ bkb,
    unsigned short* __restrict__ Qbuf, unsigned short* __restrict__ Kbuf)
{
    __shared__ float ilds[128 * 69];   // 128 chans x (64 tokens + 5 pad) = 35,328 B

    const int z = blockIdx.z;
    const float* img = (z == 0) ? qimg : kimg;
    const unsigned short* Wb = (z == 0) ? Wqb : Wkb;
    const unsigned short* bias = (z == 0) ? bqb : bkb;
    unsigned short* outTok = (z == 0) ? Qbuf : Kbuf;

    const int tid  = threadIdx.x;
    const int wave = tid >> 6;
    const int lane = tid & 63;
    const int l15  = lane & 15;
    const int quad = lane >> 4;
    const int b     = blockIdx.y;
    const int stile = blockIdx.x;

    const float* gbase = img + (size_t)b * CC * SS + stile * 64;
    #pragma unroll
    for (int i = 0; i < 8; ++i) {
        const int l = tid + 256 * i;          // 0..2047
        const int row = l >> 4, col = (l & 15) * 4;
        float4 v = *(const float4*)(gbase + (size_t)row * SS + col);
        float* d = ilds + row * 69 + col;
        d[0] = v.x; d[1] = v.y; d[2] = v.z; d[3] = v.w;
    }
    __syncthreads();

    const int tcol = wave * 16 + l15;
    sh8 a[4];
    #pragma unroll
    for (int kk = 0; kk < 4; ++kk)
        #pragma unroll
        for (int j = 0; j < 8; ++j)
            a[kk][j] = (short)rhu(ilds[(32 * kk + quad * 8 + j) * 69 + tcol]);

    f32x4 acc[8];
    #pragma unroll
    for (int nt = 0; nt < 8; ++nt) acc[nt] = (f32x4){0.f, 0.f, 0.f, 0.f};

    #pragma unroll
    for (int nt = 0; nt < 8; ++nt) {
        const unsigned short* wp = Wb + (size_t)(16 * nt + l15) * CC + quad * 8;
        #pragma unroll
        for (int kk = 0; kk < 4; ++kk) {
            sh8 bf = *(const sh8*)(wp + 32 * kk);
            acc[nt] = __builtin_amdgcn_mfma_f32_16x16x32_bf16(a[kk], bf, acc[nt], 0, 0, 0);
        }
    }

    __syncthreads();   // all ilds A-frag reads done; safe to alias
    unsigned short* oT = (unsigned short*)ilds;   // [64 s][132 o] ushorts
    #pragma unroll
    for (int nt = 0; nt < 8; ++nt) {
        const int o = 16 * nt + l15;
        const float bv = b2f(bias[o]);
        #pragma unroll
        for (int r = 0; r < 4; ++r) {
            const int sl = wave * 16 + quad * 4 + r;
            oT[sl * 132 + o] = f2b(acc[nt][r] + bv);   // 2-way banks (free)
        }
    }
    __syncthreads();

    unsigned short* orow = outTok + ((size_t)b * SS + stile * 64) * CC;
    #pragma unroll
    for (int i = 0; i < 8; ++i) {
        const int idx = tid + 256 * i;      // 0..2047
        const int s = idx >> 5, o4 = (idx & 31) * 4;
        *(ushort4*)(orow + (size_t)s * CC + o4) = *(const ushort4*)(oT + s * 132 + o4);
    }
}

// ---------------------------------------------------------------------------
// Flash attention (round-9 VERBATIM — best measured, 78.5 us).
// Packed-partial store: row (b,c), qt-tile f32 span = [256 B half0 | 256 B
// half1] bf16. Block: 4 waves x 32 q = 128 q over HKV=2048; grid 512.
// LDS 65,536 B: K dbuf 2x16 KB, V dbuf 2x16 KB; oT aliases after barrier.
// ---------------------------------------------------------------------------
__global__ __launch_bounds__(256, 2) void attn_kernel(
    const unsigned short* __restrict__ Qbuf,  // (B,S,C) bf16 token-major
    const unsigned short* __restrict__ Kbuf,  // (B,S,C) bf16 token-major
    const unsigned short* __restrict__ Vbuf,  // (B,C,S) bf16 channel-major
    float* __restrict__ Oout,                 // (B,C,S) fp32 rows w/ packed partials
    float* __restrict__ Lsum)                 // (NSPLIT,B,S) f32 partial sums
{
    __shared__ __align__(16) unsigned char smem[65536];

    const int tid  = threadIdx.x;
    const int wave = tid >> 6;
    const int lane = tid & 63;
    const int l15  = lane & 15;
    const int quad = lane >> 4;
    const int wgid = blockIdx.x;
    const int b    = wgid & 7;          // batch == XCD (L2 holds one batch's K/V)
    const int half = (wgid >> 3) & 1;   // KV half
    const int qt   = wgid >> 4;         // 0..31, 128 queries each
    const int qbase = qt * 128 + wave * 32;
    const int tok0  = half * HKV;

    const unsigned short* kbp = Kbuf + (size_t)b * SS * CC;
    const unsigned short* vbp = Vbuf + (size_t)b * CC * SS;

    // Q frags (B operand of swapped QK)
    sh8 aq[2][4];
    #pragma unroll
    for (int m = 0; m < 2; ++m) {
        const unsigned short* qp = Qbuf + ((size_t)b * SS + qbase + m * 16 + l15) * CC + quad * 8;
        #pragma unroll
        for (int kk = 0; kk < 4; ++kk) aq[m][kk] = *(const sh8*)(qp + 32 * kk);
    }

    // DMA source offsets (bytes), constant across iterations
    int kGO[4], vGO[4];
    #pragma unroll
    for (int j = 0; j < 4; ++j) {
        const int krow = wave * 16 + j * 4 + quad;
        const int sx = (krow & 3) | ((krow >> 1) & 4);
        kGO[j] = krow * 256 + (((lane & 15) ^ sx) << 4);
        const int vrow = (wave * 4 + j) * 8 + (lane >> 3);
        vGO[j] = vrow * 8192 + (((lane & 7) ^ ((lane >> 3) & 7)) << 4);
    }

    // K read addressing: permuted row per frag n; swizzle term == l15&7 for all n
    int krb[4];
    #pragma unroll
    for (int n = 0; n < 4; ++n)
        krb[n] = (32 * (n >> 1) + 8 * (l15 >> 2) + 4 * (n & 1) + (l15 & 3)) * 256;
    const int krs = l15 & 7;

    f32x4 oacc[2][8];
    #pragma unroll
    for (int m = 0; m < 2; ++m)
        #pragma unroll
        for (int ct = 0; ct < 8; ++ct) oacc[m][ct] = (f32x4){0.f, 0.f, 0.f, 0.f};
    float lsum[2] = {0.f, 0.f};

    const char* gk0 = (const char*)kbp + (size_t)tok0 * 256;
    const char* gv0 = (const char*)vbp + (size_t)tok0 * 2;

    // prologue: stage K[0], V[0] into buffer 0
    #pragma unroll
    for (int j = 0; j < 4; ++j) {
        dma16(gk0 + kGO[j], smem + (wave * 4 + j) * 1024);
        dma16(gv0 + vGO[j], smem + 32768 + (wave * 4 + j) * 1024);
    }

    for (int it = 0; it < NIT; ++it) {
        unsigned char* kb = smem + ((it & 1) << 14);
        unsigned char* vb = smem + 32768 + ((it & 1) << 14);

        // one barrier/iter: drains own DMA (vmcnt) + own LDS reads (lgkm),
        // then syncs -> K[it],V[it] resident and other buffers reusable.
        __syncthreads();

        // issue next-tile DMA into the other buffers; lands by next barrier
        if (it + 1 < NIT) {
            const char* gk = gk0 + (size_t)(it + 1) * KT * 256;
            const char* gv = gv0 + (size_t)(it + 1) * KT * 2;
            unsigned char* kbn = smem + (((it + 1) & 1) << 14);
            unsigned char* vbn = smem + 32768 + (((it + 1) & 1) << 14);
            #pragma unroll
            for (int j = 0; j < 4; ++j) {
                dma16(gk + kGO[j], kbn + (wave * 4 + j) * 1024);
                dma16(gv + vGO[j], vbn + (wave * 4 + j) * 1024);
            }
        }

        // --- S^T = K Q^T with permuted K rows ---
        f32x4 sacc[2][4];
        #pragma unroll
        for (int m = 0; m < 2; ++m)
            #pragma unroll
            for (int n = 0; n < 4; ++n) sacc[m][n] = (f32x4){0.f, 0.f, 0.f, 0.f};
        __builtin_amdgcn_s_setprio(1);
        #pragma unroll
        for (int n = 0; n < 4; ++n) {
            #pragma unroll
            for (int kk = 0; kk < 4; ++kk) {
                sh8 kf = *(const sh8*)(kb + krb[n] + (((4 * kk + quad) ^ krs) << 4));
                sacc[0][n] = __builtin_amdgcn_mfma_f32_16x16x32_bf16(kf, aq[0][kk], sacc[0][n], 0, 0, 0);
                sacc[1][n] = __builtin_amdgcn_mfma_f32_16x16x32_bf16(kf, aq[1][kk], sacc[1][n], 0, 0, 0);
            }
        }
        __builtin_amdgcn_s_setprio(0);

        // --- softmax fully in-register: exp, accumulate, pack to PV A-frags ---
        union { sh8 v; unsigned int d[4]; } pa[2][2];
        #pragma unroll
        for (int m = 0; m < 2; ++m) {
            float p[4][4];
            #pragma unroll
            for (int n = 0; n < 4; ++n)
                #pragma unroll
                for (int r = 0; r < 4; ++r) {
                    p[n][r] = __expf(sacc[m][n][r] * SCALE);
                    lsum[m] += p[n][r];
                }
            #pragma unroll
            for (int kp = 0; kp < 2; ++kp) {
                pa[m][kp].d[0] = cvtpk(p[2 * kp][0],     p[2 * kp][1]);
                pa[m][kp].d[1] = cvtpk(p[2 * kp][2],     p[2 * kp][3]);
                pa[m][kp].d[2] = cvtpk(p[2 * kp + 1][0], p[2 * kp + 1][1]);
                pa[m][kp].d[3] = cvtpk(p[2 * kp + 1][2], p[2 * kp + 1][3]);
            }
        }

        // --- PV: P from registers, V from LDS (8 frag reads per kp) ---
        __builtin_amdgcn_s_setprio(1);
        #pragma unroll
        for (int kp = 0; kp < 2; ++kp) {
            #pragma unroll
            for (int ct = 0; ct < 8; ++ct) {
                sh8 bv = *(const sh8*)(vb + (16 * ct + l15) * 128
                                          + (((kp * 4 + quad) ^ (l15 & 7)) << 4));
                oacc[0][ct] = __builtin_amdgcn_mfma_f32_16x16x32_bf16(pa[0][kp].v, bv, oacc[0][ct], 0, 0, 0);
                oacc[1][ct] = __builtin_amdgcn_mfma_f32_16x16x32_bf16(pa[1][kp].v, bv, oacc[1][ct], 0, 0, 0);
            }
        }
        __builtin_amdgcn_s_setprio(0);
    }

    // --- total row-sum: add across the 4 quads holding the same query ---
    #pragma unroll
    for (int m = 0; m < 2; ++m) {
        lsum[m] += __shfl_xor(lsum[m], 16, 64);
        lsum[m] += __shfl_xor(lsum[m], 32, 64);
    }
    if (quad == 0) {
        float* lp = Lsum + ((size_t)half * BB + b) * SS + qbase;
        lp[l15]      = lsum[0];
        lp[16 + l15] = lsum[1];
    }

    __syncthreads();   // all K/V-buffer reads done before aliasing smem

    // --- epilogue: unnormalized O -> bf16, LDS transpose, contiguous store ---
    unsigned short* oT = (unsigned short*)smem;   // [128 c][136 pad] ushorts
    #pragma unroll
    for (int m = 0; m < 2; ++m)
        #pragma unroll
        for (int ct = 0; ct < 8; ++ct) {
            const int c  = 16 * ct + l15;
            const int q0 = wave * 32 + m * 16 + quad * 4;
            ushort4 o;
            o.x = rhu(oacc[m][ct][0]); o.y = rhu(oacc[m][ct][1]);
            o.z = rhu(oacc[m][ct][2]); o.w = rhu(oacc[m][ct][3]);
            *(ushort4*)(oT + c * 136 + q0) = o;
        }
    __syncthreads();

    char* ob = (char*)Oout;
    #pragma unroll
    for (int i = 0; i < 16; ++i) {
        const int idx = tid + 256 * i;        // 0..4095
        const int c = idx >> 5, q4 = (idx & 31) * 4;
        const size_t rb = ((size_t)(b * CC + c) * SS + (size_t)qt * 128) * 4;
        *(ushort4*)(ob + rb + half * 256 + q4 * 2) = *(const ushort4*)(oT + c * 136 + q4);
    }
}

// ---------------------------------------------------------------------------
// combine: out[b][c][s] = (O0+O1)/(L0+L1) + resid(Qbuf[b][s][c]).
// Wave-exclusive rows, NO barriers/fences in the loop: each 32-lane half-wave
// owns row c = p*8 + wave*2 + hw for pass p; it reads both 256 B bf16 partial
// halves of that row (2x ushort4/lane, contiguous) and overwrites the row
// with final float4s. Read->write hazard is confined to the owning 32 lanes:
// the store's operands depend on the loads, and per-wave vmcnt ordering
// retires ALL the wave's loads before the dependent store issues. Rows are
// touched exactly once; different rows never alias. Residual staged in LDS
// (r6's measured-good coalesced pattern). One __syncthreads total.
// grid (32, 8), 256 threads.
// ---------------------------------------------------------------------------
__global__ __launch_bounds__(256) void combine_kernel(
    const unsigned short* __restrict__ Qbuf,
    const float* __restrict__ Lsum,
    float* __restrict__ out)    // rows currently hold packed partials
{
    __shared__ unsigned short rS[128][132];   // 33,792 B, token-major
    const int b = blockIdx.y, qt = blockIdx.x, tid = threadIdx.x;
    const int lane = tid & 63, wave = tid >> 6;
    const int l31 = lane & 31, hw = lane >> 5;

    // stage residual slab (128 tok x 128 c), coalesced ushort4
    const unsigned short* qb = Qbuf + ((size_t)b * SS + qt * 128) * CC;
    #pragma unroll
    for (int i = 0; i < 16; ++i) {
        const int idx = tid + 256 * i;       // 0..4095
        const int s = idx >> 5, c4 = (idx & 31) * 4;
        *(ushort4*)(&rS[s][c4]) = *(const ushort4*)(qb + (size_t)s * CC + c4);
    }

    const int s0l = l31 * 4;                 // this half-wave-lane's 4 tokens
    float4 l0 = *(const float4*)(Lsum + (size_t)b * SS + qt * 128 + s0l);
    float4 l1 = *(const float4*)(Lsum + ((size_t)BB + b) * SS + qt * 128 + s0l);
    float rinv[4];
    rinv[0] = 1.f / (l0.x + l1.x); rinv[1] = 1.f / (l0.y + l1.y);
    rinv[2] = 1.f / (l0.z + l1.z); rinv[3] = 1.f / (l0.w + l1.w);
    __syncthreads();                         // rS staged (only barrier)

    for (int p = 0; p < 16; ++p) {
        const int c = p * 8 + wave * 2 + hw;                 // exclusive row
        const size_t rb = (size_t)(b * CC + c) * SS + (size_t)qt * 128;  // f32 idx
        ushort4 p0 = *(const ushort4*)((const char*)out + rb * 4 + s0l * 2);
        ushort4 p1 = *(const ushort4*)((const char*)out + rb * 4 + 256 + s0l * 2);
        float4 o;
        o.x = (b2f(p0.x) + b2f(p1.x)) * rinv[0] + b2f(rS[s0l + 0][c]);
        o.y = (b2f(p0.y) + b2f(p1.y)) * rinv[1] + b2f(rS[s0l + 1][c]);
        o.z = (b2f(p0.z) + b2f(p1.z)) * rinv[2] + b2f(rS[s0l + 2][c]);
        o.w = (b2f(p0.w) + b2f(p1.w)) * rinv[3] + b2f(rS[s0l + 3][c]);
        *(float4*)(out + rb + s0l) = o;      // vmcnt-ordered after own loads
    }
}

extern "C" void kernel_launch(void* const* d_in, const int* in_sizes, int n_in,
                              void* d_out, int out_size, void* d_ws, size_t ws_size,
                              hipStream_t stream) {
    const float* qimg = (const float*)d_in[0];
    const float* kimg = (const float*)d_in[1];
    const float* vimg = (const float*)d_in[2];
    const float* Wq   = (const float*)d_in[3];
    const float* bq   = (const float*)d_in[4];
    const float* Wk   = (const float*)d_in[5];
    const float* bk   = (const float*)d_in[6];
    float* out = (float*)d_out;

    // workspace map (~24.3 MB): partials live inside d_out (half regions)
    unsigned short* Qbuf = (unsigned short*)d_ws;                    // 8 MB
    unsigned short* Kbuf = Qbuf + (size_t)BB * SS * CC;              // 8 MB
    unsigned short* Vbuf = Kbuf + (size_t)BB * SS * CC;              // 8 MB
    unsigned short* Wqb  = Vbuf + (size_t)BB * SS * CC;              // 32 KB
    unsigned short* Wkb  = Wqb + CC * CC;                            // 32 KB
    unsigned short* bqb  = Wkb + CC * CC;
    unsigned short* bkb  = bqb + CC;
    float* Lsum = (float*)(bkb + CC);                                // 256 KB

    cvt_kernel<<<dim3(520), 256, 0, stream>>>(vimg, Wq, Wk, bq, bk,
                                              Vbuf, Wqb, Wkb, bqb, bkb);
    proj_kernel<<<dim3(SS / 64, BB, 2), 256, 0, stream>>>(
        qimg, kimg, Wqb, Wkb, bqb, bkb, Qbuf, Kbuf);
    attn_kernel<<<dim3(NSPLIT * BB * (SS / 128)), 256, 0, stream>>>(
        Qbuf, Kbuf, Vbuf, out, Lsum);
    combine_kernel<<<dim3(SS / 128, BB), 256, 0, stream>>>(Qbuf, Lsum, out);
}

// Round 13
// 185.016 us; speedup vs baseline: 1.4274x; 1.0582x over previous
//
#include <hip/hip_runtime.h>

// Shapes fixed by the reference: B=8, C=128, H=W=64 -> S=4096. All I/O fp32.
#define BB 8
#define CC 128
#define SS 4096
#define KT 64             // kv tile per iteration
#define NSPLIT 2          // KV split factor (flash-style partial softmax)
#define HKV (SS / NSPLIT) // kv tokens per block = 2048
#define NIT (HKV / KT)    // 32 kv tiles per block
#define SCALE 0.015625f   // 1/sqrt(H*W) = 1/64

typedef __attribute__((ext_vector_type(8))) short sh8;   // 8 bf16 (MFMA A/B frag)
typedef __attribute__((ext_vector_type(4))) float f32x4; // MFMA C/D frag

__device__ __forceinline__ float b2f(unsigned short u) {
    union { unsigned int i; float f; } x; x.i = ((unsigned int)u) << 16; return x.f;
}
__device__ __forceinline__ unsigned short f2b(float f) {  // RNE
    union { float f; unsigned int i; } x; x.f = f;
    unsigned int r = x.i + 0x7fff + ((x.i >> 16) & 1);
    return (unsigned short)(r >> 16);
}
__device__ __forceinline__ unsigned short rhu(float f) {  // round-half-up, 2 VALU
    union { float f; unsigned int i; } x; x.f = f;
    return (unsigned short)((x.i + 0x8000) >> 16);
}
// pack 2 f32 -> 2 bf16 in one dword (lo = first arg). No builtin on gfx950.
__device__ __forceinline__ unsigned int cvtpk(float lo, float hi) {
    unsigned int r;
    asm("v_cvt_pk_bf16_f32 %0, %1, %2" : "=v"(r) : "v"(lo), "v"(hi));
    return r;
}

// async 16B global->LDS DMA (lane i writes lds_base + i*16; LDS base wave-uniform)
__device__ __forceinline__ void dma16(const void* g, void* l) {
    __builtin_amdgcn_global_load_lds((const __attribute__((address_space(1))) void*)g,
                                     (__attribute__((address_space(3))) void*)l,
                                     16, 0, 0);
}

// ---------------------------------------------------------------------------
// proj (fused, 3-launch pipeline): z=0 -> Q proj, z=1 -> K proj,
// z=2 -> V fp32->bf16 copy (r5-verified path).
// Weights converted ONCE PER BLOCK fp32->bf16 into LDS (not r5's
// per-operand inline cvtpk), stored with attn's proven chunk-XOR swizzle:
//   row r (256 B), chunk c (16 B) at slot c ^ (r&7)
// so the MFMA-loop read (row=16nt+l15, chunk=quad+4kk, ^(l15&7)) is the
// exact conflict-free pattern attn's K reads measure at full speed.
// Bias applied in fp32 (r5-verified numerics).
// outTok[b][s][o] = sum_c img[b][c][s] * W[o][c] + bias[o]
// grid=(64, 8, 3), 256 threads.
// ---------------------------------------------------------------------------
__global__ __launch_bounds__(256) void proj_kernel(
    const float* __restrict__ qimg, const float* __restrict__ kimg,
    const float* __restrict__ vimg,
    const float* __restrict__ Wq, const float* __restrict__ Wk,
    const float* __restrict__ bq, const float* __restrict__ bk,
    unsigned short* __restrict__ Qbuf, unsigned short* __restrict__ Kbuf,
    unsigned short* __restrict__ Vbuf)
{
    __shared__ float ilds[128 * 69];   // 35,328 B; reused: img -> weights -> oT

    const int z = blockIdx.z;
    const int b     = blockIdx.y;
    const int stile = blockIdx.x;
    const int tid   = threadIdx.x;

    if (z == 2) {   // V conversion: 64-token x 128-chan tile, coalesced float4
        const float* src = vimg + (size_t)b * CC * SS + stile * 64;
        unsigned short* dst = Vbuf + (size_t)b * CC * SS + stile * 64;
        #pragma unroll
        for (int i = 0; i < 8; ++i) {
            const int idx = tid + i * 256;        // 0..2047
            const int c = idx >> 4, t4 = (idx & 15) * 4;
            float4 v = *(const float4*)(src + (size_t)c * SS + t4);
            ushort4 o;
            o.x = f2b(v.x); o.y = f2b(v.y); o.z = f2b(v.z); o.w = f2b(v.w);
            *(ushort4*)(dst + (size_t)c * SS + t4) = o;
        }
        return;
    }

    const float* img  = (z == 0) ? qimg : kimg;
    const float* Wf   = (z == 0) ? Wq : Wk;
    const float* bias = (z == 0) ? bq : bk;
    unsigned short* outTok = (z == 0) ? Qbuf : Kbuf;

    const int wave = tid >> 6;
    const int lane = tid & 63;
    const int l15  = lane & 15;
    const int quad = lane >> 4;

    // stage 128x64 fp32 img tile, coalesced (64B contiguous per 16 lanes)
    const float* gbase = img + (size_t)b * CC * SS + stile * 64;
    #pragma unroll
    for (int i = 0; i < 8; ++i) {
        const int l = tid + 256 * i;          // 0..2047
        const int row = l >> 4, col = (l & 15) * 4;
        float4 v = *(const float4*)(gbase + (size_t)row * SS + col);
        float* d = ilds + row * 69 + col;
        d[0] = v.x; d[1] = v.y; d[2] = v.z; d[3] = v.w;
    }
    __syncthreads();

    // A-frags from LDS: A[m=l15][k=32kk+quad*8+j] = img[c=k][token]
    const int tcol = wave * 16 + l15;
    sh8 a[4];
    #pragma unroll
    for (int kk = 0; kk < 4; ++kk)
        #pragma unroll
        for (int j = 0; j < 8; ++j)
            a[kk][j] = (short)rhu(ilds[(32 * kk + quad * 8 + j) * 69 + tcol]);

    __syncthreads();   // A-frag reads done; ilds space reusable for weights

    // stage weights fp32 -> bf16 into wlds (chunk-XOR swizzled, 32,768 B)
    unsigned short* wlds = (unsigned short*)ilds;   // [128 rows][256 B]
    #pragma unroll
    for (int i = 0; i < 8; ++i) {
        const int idx = tid + 256 * i;        // 0..2047
        const int row = idx >> 4, ch = idx & 15;
        const float* wp = Wf + (size_t)row * CC + ch * 8;
        float4 w0 = *(const float4*)(wp);
        float4 w1 = *(const float4*)(wp + 4);
        uint4 pk;
        pk.x = cvtpk(w0.x, w0.y); pk.y = cvtpk(w0.z, w0.w);
        pk.z = cvtpk(w1.x, w1.y); pk.w = cvtpk(w1.z, w1.w);
        *(uint4*)((char*)wlds + row * 256 + ((ch ^ (row & 7)) << 4)) = pk;
    }
    __syncthreads();

    f32x4 acc[8];
    #pragma unroll
    for (int nt = 0; nt < 8; ++nt) acc[nt] = (f32x4){0.f, 0.f, 0.f, 0.f};

    #pragma unroll
    for (int nt = 0; nt < 8; ++nt) {
        const int wrow = 16 * nt + l15;
        #pragma unroll
        for (int kk = 0; kk < 4; ++kk) {
            sh8 bf = *(const sh8*)((const char*)wlds + wrow * 256
                                   + (((quad + 4 * kk) ^ (l15 & 7)) << 4));
            acc[nt] = __builtin_amdgcn_mfma_f32_16x16x32_bf16(a[kk], bf, acc[nt], 0, 0, 0);
        }
    }

    __syncthreads();   // all wlds reads done; safe to alias with oT
    unsigned short* oT = (unsigned short*)ilds;   // [64 s][132 o] ushorts
    #pragma unroll
    for (int nt = 0; nt < 8; ++nt) {
        const int o = 16 * nt + l15;
        const float bv = bias[o];
        #pragma unroll
        for (int r = 0; r < 4; ++r) {
            const int sl = wave * 16 + quad * 4 + r;
            oT[sl * 132 + o] = f2b(acc[nt][r] + bv);   // 2-way banks (free)
        }
    }
    __syncthreads();

    unsigned short* orow = outTok + ((size_t)b * SS + stile * 64) * CC;
    #pragma unroll
    for (int i = 0; i < 8; ++i) {
        const int idx = tid + 256 * i;      // 0..2047
        const int s = idx >> 5, o4 = (idx & 31) * 4;
        *(ushort4*)(orow + (size_t)s * CC + o4) = *(const ushort4*)(oT + s * 132 + o4);
    }
}

// ---------------------------------------------------------------------------
// Flash attention (round-9/12 VERBATIM — best measured, 78.5-80.6 us).
// Packed-partial store: row (b,c), qt-tile f32 span = [256 B half0 | 256 B
// half1] bf16. Block: 4 waves x 32 q = 128 q over HKV=2048; grid 512.
// LDS 65,536 B: K dbuf 2x16 KB, V dbuf 2x16 KB; oT aliases after barrier.
// ---------------------------------------------------------------------------
__global__ __launch_bounds__(256, 2) void attn_kernel(
    const unsigned short* __restrict__ Qbuf,  // (B,S,C) bf16 token-major
    const unsigned short* __restrict__ Kbuf,  // (B,S,C) bf16 token-major
    const unsigned short* __restrict__ Vbuf,  // (B,C,S) bf16 channel-major
    float* __restrict__ Oout,                 // (B,C,S) fp32 rows w/ packed partials
    float* __restrict__ Lsum)                 // (NSPLIT,B,S) f32 partial sums
{
    __shared__ __align__(16) unsigned char smem[65536];

    const int tid  = threadIdx.x;
    const int wave = tid >> 6;
    const int lane = tid & 63;
    const int l15  = lane & 15;
    const int quad = lane >> 4;
    const int wgid = blockIdx.x;
    const int b    = wgid & 7;          // batch == XCD (L2 holds one batch's K/V)
    const int half = (wgid >> 3) & 1;   // KV half
    const int qt   = wgid >> 4;         // 0..31, 128 queries each
    const int qbase = qt * 128 + wave * 32;
    const int tok0  = half * HKV;

    const unsigned short* kbp = Kbuf + (size_t)b * SS * CC;
    const unsigned short* vbp = Vbuf + (size_t)b * CC * SS;

    // Q frags (B operand of swapped QK)
    sh8 aq[2][4];
    #pragma unroll
    for (int m = 0; m < 2; ++m) {
        const unsigned short* qp = Qbuf + ((size_t)b * SS + qbase + m * 16 + l15) * CC + quad * 8;
        #pragma unroll
        for (int kk = 0; kk < 4; ++kk) aq[m][kk] = *(const sh8*)(qp + 32 * kk);
    }

    // DMA source offsets (bytes), constant across iterations
    int kGO[4], vGO[4];
    #pragma unroll
    for (int j = 0; j < 4; ++j) {
        const int krow = wave * 16 + j * 4 + quad;
        const int sx = (krow & 3) | ((krow >> 1) & 4);
        kGO[j] = krow * 256 + (((lane & 15) ^ sx) << 4);
        const int vrow = (wave * 4 + j) * 8 + (lane >> 3);
        vGO[j] = vrow * 8192 + (((lane & 7) ^ ((lane >> 3) & 7)) << 4);
    }

    // K read addressing: permuted row per frag n; swizzle term == l15&7 for all n
    int krb[4];
    #pragma unroll
    for (int n = 0; n < 4; ++n)
        krb[n] = (32 * (n >> 1) + 8 * (l15 >> 2) + 4 * (n & 1) + (l15 & 3)) * 256;
    const int krs = l15 & 7;

    f32x4 oacc[2][8];
    #pragma unroll
    for (int m = 0; m < 2; ++m)
        #pragma unroll
        for (int ct = 0; ct < 8; ++ct) oacc[m][ct] = (f32x4){0.f, 0.f, 0.f, 0.f};
    float lsum[2] = {0.f, 0.f};

    const char* gk0 = (const char*)kbp + (size_t)tok0 * 256;
    const char* gv0 = (const char*)vbp + (size_t)tok0 * 2;

    // prologue: stage K[0], V[0] into buffer 0
    #pragma unroll
    for (int j = 0; j < 4; ++j) {
        dma16(gk0 + kGO[j], smem + (wave * 4 + j) * 1024);
        dma16(gv0 + vGO[j], smem + 32768 + (wave * 4 + j) * 1024);
    }

    for (int it = 0; it < NIT; ++it) {
        unsigned char* kb = smem + ((it & 1) << 14);
        unsigned char* vb = smem + 32768 + ((it & 1) << 14);

        // one barrier/iter: drains own DMA (vmcnt) + own LDS reads (lgkm),
        // then syncs -> K[it],V[it] resident and other buffers reusable.
        __syncthreads();

        // issue next-tile DMA into the other buffers; lands by next barrier
        if (it + 1 < NIT) {
            const char* gk = gk0 + (size_t)(it + 1) * KT * 256;
            const char* gv = gv0 + (size_t)(it + 1) * KT * 2;
            unsigned char* kbn = smem + (((it + 1) & 1) << 14);
            unsigned char* vbn = smem + 32768 + (((it + 1) & 1) << 14);
            #pragma unroll
            for (int j = 0; j < 4; ++j) {
                dma16(gk + kGO[j], kbn + (wave * 4 + j) * 1024);
                dma16(gv + vGO[j], vbn + (wave * 4 + j) * 1024);
            }
        }

        // --- S^T = K Q^T with permuted K rows ---
        f32x4 sacc[2][4];
        #pragma unroll
        for (int m = 0; m < 2; ++m)
            #pragma unroll
            for (int n = 0; n < 4; ++n) sacc[m][n] = (f32x4){0.f, 0.f, 0.f, 0.f};
        __builtin_amdgcn_s_setprio(1);
        #pragma unroll
        for (int n = 0; n < 4; ++n) {
            #pragma unroll
            for (int kk = 0; kk < 4; ++kk) {
                sh8 kf = *(const sh8*)(kb + krb[n] + (((4 * kk + quad) ^ krs) << 4));
                sacc[0][n] = __builtin_amdgcn_mfma_f32_16x16x32_bf16(kf, aq[0][kk], sacc[0][n], 0, 0, 0);
                sacc[1][n] = __builtin_amdgcn_mfma_f32_16x16x32_bf16(kf, aq[1][kk], sacc[1][n], 0, 0, 0);
            }
        }
        __builtin_amdgcn_s_setprio(0);

        // --- softmax fully in-register: exp, accumulate, pack to PV A-frags ---
        union { sh8 v; unsigned int d[4]; } pa[2][2];
        #pragma unroll
        for (int m = 0; m < 2; ++m) {
            float p[4][4];
            #pragma unroll
            for (int n = 0; n < 4; ++n)
                #pragma unroll
                for (int r = 0; r < 4; ++r) {
                    p[n][r] = __expf(sacc[m][n][r] * SCALE);
                    lsum[m] += p[n][r];
                }
            #pragma unroll
            for (int kp = 0; kp < 2; ++kp) {
                pa[m][kp].d[0] = cvtpk(p[2 * kp][0],     p[2 * kp][1]);
                pa[m][kp].d[1] = cvtpk(p[2 * kp][2],     p[2 * kp][3]);
                pa[m][kp].d[2] = cvtpk(p[2 * kp + 1][0], p[2 * kp + 1][1]);
                pa[m][kp].d[3] = cvtpk(p[2 * kp + 1][2], p[2 * kp + 1][3]);
            }
        }

        // --- PV: P from registers, V from LDS (8 frag reads per kp) ---
        __builtin_amdgcn_s_setprio(1);
        #pragma unroll
        for (int kp = 0; kp < 2; ++kp) {
            #pragma unroll
            for (int ct = 0; ct < 8; ++ct) {
                sh8 bv = *(const sh8*)(vb + (16 * ct + l15) * 128
                                          + (((kp * 4 + quad) ^ (l15 & 7)) << 4));
                oacc[0][ct] = __builtin_amdgcn_mfma_f32_16x16x32_bf16(pa[0][kp].v, bv, oacc[0][ct], 0, 0, 0);
                oacc[1][ct] = __builtin_amdgcn_mfma_f32_16x16x32_bf16(pa[1][kp].v, bv, oacc[1][ct], 0, 0, 0);
            }
        }
        __builtin_amdgcn_s_setprio(0);
    }

    // --- total row-sum: add across the 4 quads holding the same query ---
    #pragma unroll
    for (int m = 0; m < 2; ++m) {
        lsum[m] += __shfl_xor(lsum[m], 16, 64);
        lsum[m] += __shfl_xor(lsum[m], 32, 64);
    }
    if (quad == 0) {
        float* lp = Lsum + ((size_t)half * BB + b) * SS + qbase;
        lp[l15]      = lsum[0];
        lp[16 + l15] = lsum[1];
    }

    __syncthreads();   // all K/V-buffer reads done before aliasing smem

    // --- epilogue: unnormalized O -> bf16, LDS transpose, contiguous store ---
    unsigned short* oT = (unsigned short*)smem;   // [128 c][136 pad] ushorts
    #pragma unroll
    for (int m = 0; m < 2; ++m)
        #pragma unroll
        for (int ct = 0; ct < 8; ++ct) {
            const int c  = 16 * ct + l15;
            const int q0 = wave * 32 + m * 16 + quad * 4;
            ushort4 o;
            o.x = rhu(oacc[m][ct][0]); o.y = rhu(oacc[m][ct][1]);
            o.z = rhu(oacc[m][ct][2]); o.w = rhu(oacc[m][ct][3]);
            *(ushort4*)(oT + c * 136 + q0) = o;
        }
    __syncthreads();

    char* ob = (char*)Oout;
    #pragma unroll
    for (int i = 0; i < 16; ++i) {
        const int idx = tid + 256 * i;        // 0..4095
        const int c = idx >> 5, q4 = (idx & 31) * 4;
        const size_t rb = ((size_t)(b * CC + c) * SS + (size_t)qt * 128) * 4;
        *(ushort4*)(ob + rb + half * 256 + q4 * 2) = *(const ushort4*)(oT + c * 136 + q4);
    }
}

// ---------------------------------------------------------------------------
// combine (round-12 VERBATIM): out = (O0+O1)/(L0+L1) + resid.
// Wave-exclusive rows, no barriers/fences in the loop; residual staged in
// LDS. grid (32, 8), 256 threads.
// ---------------------------------------------------------------------------
__global__ __launch_bounds__(256) void combine_kernel(
    const unsigned short* __restrict__ Qbuf,
    const float* __restrict__ Lsum,
    float* __restrict__ out)    // rows currently hold packed partials
{
    __shared__ unsigned short rS[128][132];   // 33,792 B, token-major
    const int b = blockIdx.y, qt = blockIdx.x, tid = threadIdx.x;
    const int lane = tid & 63, wave = tid >> 6;
    const int l31 = lane & 31, hw = lane >> 5;

    // stage residual slab (128 tok x 128 c), coalesced ushort4
    const unsigned short* qb = Qbuf + ((size_t)b * SS + qt * 128) * CC;
    #pragma unroll
    for (int i = 0; i < 16; ++i) {
        const int idx = tid + 256 * i;       // 0..4095
        const int s = idx >> 5, c4 = (idx & 31) * 4;
        *(ushort4*)(&rS[s][c4]) = *(const ushort4*)(qb + (size_t)s * CC + c4);
    }

    const int s0l = l31 * 4;                 // this half-wave-lane's 4 tokens
    float4 l0 = *(const float4*)(Lsum + (size_t)b * SS + qt * 128 + s0l);
    float4 l1 = *(const float4*)(Lsum + ((size_t)BB + b) * SS + qt * 128 + s0l);
    float rinv[4];
    rinv[0] = 1.f / (l0.x + l1.x); rinv[1] = 1.f / (l0.y + l1.y);
    rinv[2] = 1.f / (l0.z + l1.z); rinv[3] = 1.f / (l0.w + l1.w);
    __syncthreads();                         // rS staged (only barrier)

    for (int p = 0; p < 16; ++p) {
        const int c = p * 8 + wave * 2 + hw;                 // exclusive row
        const size_t rb = (size_t)(b * CC + c) * SS + (size_t)qt * 128;  // f32 idx
        ushort4 p0 = *(const ushort4*)((const char*)out + rb * 4 + s0l * 2);
        ushort4 p1 = *(const ushort4*)((const char*)out + rb * 4 + 256 + s0l * 2);
        float4 o;
        o.x = (b2f(p0.x) + b2f(p1.x)) * rinv[0] + b2f(rS[s0l + 0][c]);
        o.y = (b2f(p0.y) + b2f(p1.y)) * rinv[1] + b2f(rS[s0l + 1][c]);
        o.z = (b2f(p0.z) + b2f(p1.z)) * rinv[2] + b2f(rS[s0l + 2][c]);
        o.w = (b2f(p0.w) + b2f(p1.w)) * rinv[3] + b2f(rS[s0l + 3][c]);
        *(float4*)(out + rb + s0l) = o;      // vmcnt-ordered after own loads
    }
}

extern "C" void kernel_launch(void* const* d_in, const int* in_sizes, int n_in,
                              void* d_out, int out_size, void* d_ws, size_t ws_size,
                              hipStream_t stream) {
    const float* qimg = (const float*)d_in[0];
    const float* kimg = (const float*)d_in[1];
    const float* vimg = (const float*)d_in[2];
    const float* Wq   = (const float*)d_in[3];
    const float* bq   = (const float*)d_in[4];
    const float* Wk   = (const float*)d_in[5];
    const float* bk   = (const float*)d_in[6];
    float* out = (float*)d_out;

    // workspace map (~24.25 MB): partials live inside d_out (half regions)
    unsigned short* Qbuf = (unsigned short*)d_ws;                    // 8 MB
    unsigned short* Kbuf = Qbuf + (size_t)BB * SS * CC;              // 8 MB
    unsigned short* Vbuf = Kbuf + (size_t)BB * SS * CC;              // 8 MB
    float* Lsum = (float*)(Vbuf + (size_t)BB * SS * CC);             // 256 KB

    proj_kernel<<<dim3(SS / 64, BB, 3), 256, 0, stream>>>(
        qimg, kimg, vimg, Wq, Wk, bq, bk, Qbuf, Kbuf, Vbuf);
    attn_kernel<<<dim3(NSPLIT * BB * (SS / 128)), 256, 0, stream>>>(
        Qbuf, Kbuf, Vbuf, out, Lsum);
    combine_kernel<<<dim3(SS / 128, BB), 256, 0, stream>>>(Qbuf, Lsum, out);
}